// Round 1
// baseline (153.849 us; speedup 1.0000x reference)
//
#include <hip/hip_runtime.h>
#include <hip/hip_bf16.h>

// HT layer via bf16 32x32x16 MFMA, one wave per batch element, 4 waves per block.
//   Y[b] = sum_p A_p(64x64) @ X_b(64x64) @ W_p(64x64) + bias
// Step A: T^T[kl][ac] = sum_ij X^T[kl][ij] * A_p^T[ij][ac]   (M=kl, N=ac, K=ij)
// Step B: Y^T[de][ac] += sum_kl W^T[de][kl] * T^T[kl][ac]    (M=de, N=ac, K=kl)
// mfma_f32_32x32x16_bf16 layouts:
//   A: A[m=lane&31][k=(lane>>5)*8+j]   B: B[k=(lane>>5)*8+j][n=lane&31]
//   C/D: col=lane&31, row=(reg&3)+8*(reg>>2)+4*(lane>>5)   (guide m74/m101)
// Key trick: C/D row-sets of the two lane-halves are exactly complementary to the
// B-operand's k-sets, so the T^T C->B repack is 8 v_cvt_pk_bf16_f32 +
// 4 v_permlane32_swap_b32 per tile -- NO LDS in the p-loop at all.
// LDS is used only for the one-time epilogue transpose (Y^T -> Y, coalesced f32x2
// stores), pitch 66 floats to balance banks.

typedef short bf16x8 __attribute__((ext_vector_type(8)));
typedef float f32x16 __attribute__((ext_vector_type(16)));

union Frag8 {
    bf16x8 v;
    unsigned int u4[4];
};

static __device__ __forceinline__ unsigned int pkbf(float a, float b) {
    // v_cvt_pk_bf16_f32 on gfx950 (RNE), a -> low 16, b -> high 16
    __hip_bfloat162 h = __float22bfloat162_rn(float2{a, b});
    return *reinterpret_cast<unsigned int*>(&h);
}

static __device__ __forceinline__ unsigned short f2bf(float f) {
    unsigned int u = __float_as_uint(f);
    u = (u + 0x7FFFu + ((u >> 16) & 1u)) >> 16;   // RNE (software, precompute only)
    return (unsigned short)u;
}

// Precompute bf16 fragments of A_p^T (step-A B-operand) and W_p^T (step-B A-operand).
// Layout: frags[isW][p(8)][t(2)][kc(4)][lane(64)][j(8)] bf16, 64KB each.
// Both layouts share the same decode:
//   contraction index k = kc*16 + (lane>>5)*8 + j   (ij for AF, kl for WF)
//   other index       n = t*32 + (lane&31)          (ac for AF, de for WF)
// AF element = WL[ij][ac][p],  WF element = WR[kl][de][p]
__global__ void ht_precompute(const float* __restrict__ F0, const float* __restrict__ F1,
                              const float* __restrict__ F2, const float* __restrict__ F3,
                              const float* __restrict__ CL, const float* __restrict__ CR,
                              unsigned short* __restrict__ frags) {
    int idx = blockIdx.x * blockDim.x + threadIdx.x;   // 0..65535
    int isW  = idx >> 15;
    int r15  = idx & 32767;
    int p    = r15 >> 12;
    int t    = (r15 >> 11) & 1;
    int kc   = (r15 >> 9) & 3;
    int lane = (r15 >> 3) & 63;
    int j    = r15 & 7;
    int n = t * 32 + (lane & 31);
    int k = kc * 16 + ((lane >> 5) & 1) * 8 + j;
    const float* Fa = isW ? F2 : F0;
    const float* Fb = isW ? F3 : F1;
    const float* C  = isW ? CR : CL;
    int i1 = k >> 3, i2 = k & 7, o1 = n >> 3, o2 = n & 7;
    float acc = 0.f;
    for (int r = 0; r < 8; ++r) {
        float fa = Fa[(i1 * 8 + o1) * 8 + r];
        for (int s = 0; s < 8; ++s)
            acc += fa * Fb[(i2 * 8 + o2) * 8 + s] * C[(r * 8 + s) * 8 + p];
    }
    frags[(size_t)isW * 32768 + ((((p * 2 + t) * 4 + kc) << 6) + lane) * 8 + j] = f2bf(acc);
}

#define Y_PITCH 66   // f32 per row of the epilogue staging buffer (bank-balanced)

__global__ __launch_bounds__(256, 2) void ht_main(const float* __restrict__ x,
                                                  const unsigned short* __restrict__ frags,
                                                  const float* __restrict__ bias,
                                                  float* __restrict__ out) {
    __shared__ float Ybuf[4][32 * Y_PITCH];   // 33,792 B: epilogue transpose only
    const int tid  = threadIdx.x;
    const int lane = tid & 63;
    const int w    = __builtin_amdgcn_readfirstlane(tid >> 6);
    const int b    = blockIdx.x * 4 + w;
    const int l31  = lane & 31;
    const int hi   = lane >> 5;

    // ---- X^T A-fragments: xf[rb][kc], element j = X^T[kl=rb*32+l31][ij=kc*16+hi*8+j]
    Frag8 xf[2][4];
    const float* xb = x + ((size_t)b << 12);
#pragma unroll
    for (int rb = 0; rb < 2; ++rb)
#pragma unroll
        for (int kc = 0; kc < 4; ++kc) {
            const float* src = xb + (kc * 16 + hi * 8) * 64 + rb * 32 + l31;
#pragma unroll
            for (int j = 0; j < 8; j += 2)
                xf[rb][kc].u4[j >> 1] = pkbf(src[j * 64], src[(j + 1) * 64]);
        }

    f32x16 acc[2][2];   // Y^T tiles: [mt over de][cb over ac]
#pragma unroll
    for (int i = 0; i < 2; ++i)
#pragma unroll
        for (int j = 0; j < 2; ++j)
#pragma unroll
            for (int e = 0; e < 16; ++e)
                acc[i][j][e] = 0.f;

    const unsigned short* AF = frags;          // A_p^T frags (B-operand of step A)
    const unsigned short* WF = frags + 32768;  // W_p^T frags (A-operand of step B)

#pragma unroll 2
    for (int p = 0; p < 8; ++p) {
        Frag8 af[2][4], wf[2][4];
#pragma unroll
        for (int t = 0; t < 2; ++t)
#pragma unroll
            for (int kc = 0; kc < 4; ++kc) {
                int off = (((p * 2 + t) * 4 + kc) << 9) + lane * 8;
                af[t][kc].v = *(const bf16x8*)(AF + off);
                wf[t][kc].v = *(const bf16x8*)(WF + off);
            }
#pragma unroll
        for (int rb = 0; rb < 2; ++rb) {
#pragma unroll
            for (int cb = 0; cb < 2; ++cb) {
                // ---- Step A: T^T tile (kl rows rb*32.., ac cols cb*32..)
                f32x16 t;
#pragma unroll
                for (int e = 0; e < 16; ++e) t[e] = 0.f;
#pragma unroll
                for (int kc = 0; kc < 4; ++kc)
                    t = __builtin_amdgcn_mfma_f32_32x32x16_bf16(xf[rb][kc].v, af[cb][kc].v, t, 0, 0, 0);
                // ---- Repack C/D -> two B-operand frags (kcg = 2rb, 2rb+1), in-register.
                // wd[h] rows (+4*hi): h0:0,1 h1:2,3 h2:8,9 h3:10,11 h4:16,17 h5:18,19 h6:24,25 h7:26,27
                unsigned int wd[8];
#pragma unroll
                for (int h = 0; h < 8; ++h) wd[h] = pkbf(t[2 * h], t[2 * h + 1]);
                auto s02 = __builtin_amdgcn_permlane32_swap(wd[0], wd[2], false, false);
                auto s13 = __builtin_amdgcn_permlane32_swap(wd[1], wd[3], false, false);
                auto s46 = __builtin_amdgcn_permlane32_swap(wd[4], wd[6], false, false);
                auto s57 = __builtin_amdgcn_permlane32_swap(wd[5], wd[7], false, false);
                Frag8 tb0, tb1;
                tb0.u4[0] = s02[0]; tb0.u4[1] = s13[0]; tb0.u4[2] = s02[1]; tb0.u4[3] = s13[1];
                tb1.u4[0] = s46[0]; tb1.u4[1] = s57[0]; tb1.u4[2] = s46[1]; tb1.u4[3] = s57[1];
                // ---- Step B: Y^T[de][ac] += W^T[de][kl] * T^T[kl][ac]
                acc[0][cb] = __builtin_amdgcn_mfma_f32_32x32x16_bf16(wf[0][2 * rb].v,     tb0.v, acc[0][cb], 0, 0, 0);
                acc[0][cb] = __builtin_amdgcn_mfma_f32_32x32x16_bf16(wf[0][2 * rb + 1].v, tb1.v, acc[0][cb], 0, 0, 0);
                acc[1][cb] = __builtin_amdgcn_mfma_f32_32x32x16_bf16(wf[1][2 * rb].v,     tb0.v, acc[1][cb], 0, 0, 0);
                acc[1][cb] = __builtin_amdgcn_mfma_f32_32x32x16_bf16(wf[1][2 * rb + 1].v, tb1.v, acc[1][cb], 0, 0, 0);
            }
        }
    }

    // ---- Epilogue: per-cb LDS transpose (Y^T lane=col -> coalesced row stores) + bias
    float* Yw = &Ybuf[w][0];
    float* ob = out + ((size_t)b << 12);
#pragma unroll
    for (int cb = 0; cb < 2; ++cb) {
        // stage: lane holds col ac = cb*32+l31; reg r -> de = mt*32 + (r&3)+8*(r>>2)+4*hi
#pragma unroll
        for (int mt = 0; mt < 2; ++mt)
#pragma unroll
            for (int rp = 0; rp < 8; ++rp) {
                int de = mt * 32 + 8 * (rp >> 1) + 2 * (rp & 1) + 4 * hi;
                float2 v;
                v.x = acc[mt][cb][2 * rp];
                v.y = acc[mt][cb][2 * rp + 1];
                *(float2*)(&Yw[l31 * Y_PITCH + de]) = v;   // 8B store, 8B-aligned
            }
        // read transposed + bias + coalesced store (512B contiguous per instr)
#pragma unroll
        for (int i = 0; i < 16; ++i) {
            int acl = 2 * i + hi;
            float2 v = *(float2*)(&Yw[acl * Y_PITCH + 2 * l31]);
            int o = (cb * 32 + acl) * 64 + 2 * l31;
            float2 bv = *(const float2*)(bias + o);
            v.x += bv.x;
            v.y += bv.y;
            *(float2*)(ob + o) = v;
        }
    }
}

extern "C" void kernel_launch(void* const* d_in, const int* in_sizes, int n_in,
                              void* d_out, int out_size, void* d_ws, size_t ws_size,
                              hipStream_t stream) {
    const float* x    = (const float*)d_in[0];
    const float* F0   = (const float*)d_in[1];
    const float* F1   = (const float*)d_in[2];
    const float* F2   = (const float*)d_in[3];
    const float* F3   = (const float*)d_in[4];
    const float* CL   = (const float*)d_in[5];
    const float* CR   = (const float*)d_in[6];
    const float* bias = (const float*)d_in[7];
    float* out = (float*)d_out;
    unsigned short* frags = (unsigned short*)d_ws;   // 128 KB

    const int B = in_sizes[0] / 4096;   // 4096

    ht_precompute<<<256, 256, 0, stream>>>(F0, F1, F2, F3, CL, CR, frags);
    ht_main<<<B / 4, 256, 0, stream>>>(x, frags, bias, out);
}

// Round 2
// 147.605 us; speedup vs baseline: 1.0423x; 1.0423x over previous
//
#include <hip/hip_runtime.h>
#include <hip/hip_bf16.h>

// HT layer via bf16 32x32x16 MFMA, one wave per batch element, 4 waves per block.
//   Y[b] = sum_p A_p(64x64) @ X_b(64x64) @ W_p(64x64) + bias
// Step A: T^T[kl][ac] = sum_ij X^T[kl][ij] * A_p^T[ij][ac]   (M=kl, N=ac, K=ij)
// Step B: Y^T[de][ac] += sum_kl W^T[de][kl] * T^T[kl][ac]    (M=de, N=ac, K=kl)
// mfma_f32_32x32x16_bf16 layouts:
//   A: A[m=lane&31][k=(lane>>5)*8+j]   B: B[k=(lane>>5)*8+j][n=lane&31]
//   C/D: col=lane&31, row=(reg&3)+8*(reg>>2)+4*(lane>>5)
// T^T C->B repack: 8 v_cvt_pk_bf16_f32 + 4 v_permlane32_swap per tile, no LDS
// in the compute chain. Frags (A_p^T / W_p^T operands) are staged per-block
// into LDS via global_load_lds (16B), double-buffered with counted vmcnt(4):
// the 4 waves of a block share one 16KB/p frag read instead of 4x from L2.

typedef short bf16x8 __attribute__((ext_vector_type(8)));
typedef float f32x16 __attribute__((ext_vector_type(16)));

union Frag8 {
    bf16x8 v;
    unsigned int u4[4];
};

static __device__ __forceinline__ unsigned int pkbf(float a, float b) {
    // v_cvt_pk_bf16_f32 on gfx950 (RNE), a -> low 16, b -> high 16
    __hip_bfloat162 h = __float22bfloat162_rn(float2{a, b});
    return *reinterpret_cast<unsigned int*>(&h);
}

// ---------------------------------------------------------------------------
// Precompute bf16 fragments of A_p^T (step-A B-operand) and W_p^T (step-B
// A-operand). One block per (isW, p); two-stage contraction entirely in LDS.
// Layout: frags[isW][p(8)][t(2)][kc(4)][lane(64)][j(8)] bf16, 64KB each half.
//   contraction index k = kc*16 + (lane>>5)*8 + j   (ij for AF, kl for WF)
//   other index       n = t*32 + (lane&31)          (ac for AF, de for WF)
// AF element = WL[ij][ac][p],  WF element = WR[kl][de][p]
// ---------------------------------------------------------------------------
__global__ __launch_bounds__(256) void ht_precompute(
        const float* __restrict__ F0, const float* __restrict__ F1,
        const float* __restrict__ F2, const float* __restrict__ F3,
        const float* __restrict__ CL, const float* __restrict__ CR,
        unsigned short* __restrict__ frags) {
    __shared__ float sFa[512], sFb[512], sC[512], sG[512];
    const int isW = blockIdx.x >> 3;
    const int p   = blockIdx.x & 7;
    const float* Fa = isW ? F2 : F0;   // (in, out, rank) = 8x8x8
    const float* Fb = isW ? F3 : F1;
    const float* C  = isW ? CR : CL;   // (r, s, p) = 8x8x8
    const int tid = threadIdx.x;

    for (int u = tid; u < 512; u += 256) {
        sFa[u] = Fa[u]; sFb[u] = Fb[u]; sC[u] = C[u];
    }
    __syncthreads();

    // stage 1: G[r][jc] = sum_s Fb[jc*8+s] * C[(r*8+s)*8+p]   (512 entries)
#pragma unroll
    for (int e = 0; e < 2; ++e) {
        int u = tid + e * 256;
        int r = u >> 6, jc = u & 63;
        float acc = 0.f;
#pragma unroll
        for (int s = 0; s < 8; ++s)
            acc += sFb[jc * 8 + s] * sC[(r * 8 + s) * 8 + p];
        sG[u] = acc;   // sG[r*64 + jc]
    }
    __syncthreads();

    // stage 2: out[k=i1*8+j][n] = sum_r Fa[(i1*8+a)*8+r] * G[r][j*8+c]
    // group g = (i1, n); 8 consecutive j -> one 16B frag store.
#pragma unroll
    for (int e = 0; e < 2; ++e) {
        int g  = tid + e * 256;
        int i1 = g >> 6, n = g & 63;
        int a  = n >> 3, c = n & 7;
        float fa[8];
#pragma unroll
        for (int r = 0; r < 8; ++r) fa[r] = sFa[(i1 * 8 + a) * 8 + r];
        unsigned int pk[4];
#pragma unroll
        for (int jp = 0; jp < 4; ++jp) {
            float o0 = 0.f, o1 = 0.f;
#pragma unroll
            for (int r = 0; r < 8; ++r) {
                o0 += fa[r] * sG[r * 64 + (2 * jp) * 8 + c];
                o1 += fa[r] * sG[r * 64 + (2 * jp + 1) * 8 + c];
            }
            pk[jp] = pkbf(o0, o1);
        }
        int t = n >> 5, kc = i1 >> 1, lane_ = (i1 & 1) * 32 + (n & 31);
        unsigned int* dst = (unsigned int*)(frags + (size_t)isW * 32768 +
                                            ((((p * 2 + t) * 4 + kc) << 6) + lane_) * 8);
        *(uint4*)dst = uint4{pk[0], pk[1], pk[2], pk[3]};
    }
}

#define Y_PITCH 66   // f32 per row of the epilogue staging buffer (bank-balanced)

__global__ __launch_bounds__(256, 2) void ht_main(const float* __restrict__ x,
                                                  const unsigned short* __restrict__ frags,
                                                  const float* __restrict__ bias,
                                                  float* __restrict__ out) {
    // LDS: [0,16K) stage buf0, [16K,32K) stage buf1  (each: AF 8K | WF 8K)
    // After the p-loop the whole region is reused as the epilogue Ybuf (33792B).
    __shared__ __align__(16) char smem[34816];
    const int tid  = threadIdx.x;
    const int lane = tid & 63;
    const int w    = __builtin_amdgcn_readfirstlane(tid >> 6);
    const int b    = blockIdx.x * 4 + w;
    const int l31  = lane & 31;
    const int hi   = lane >> 5;

    // ---- X^T A-fragments: xf[rb][kc], element j = X^T[kl=rb*32+l31][ij=kc*16+hi*8+j]
    Frag8 xf[2][4];
    const float* xb = x + ((size_t)b << 12);
#pragma unroll
    for (int rb = 0; rb < 2; ++rb)
#pragma unroll
        for (int kc = 0; kc < 4; ++kc) {
            const float* src = xb + (kc * 16 + hi * 8) * 64 + rb * 32 + l31;
#pragma unroll
            for (int j = 0; j < 8; j += 2)
                xf[rb][kc].u4[j >> 1] = pkbf(src[j * 64], src[(j + 1) * 64]);
        }

    f32x16 acc[2][2];   // Y^T tiles: [mt over de][cb over ac]
#pragma unroll
    for (int i = 0; i < 2; ++i)
#pragma unroll
        for (int j = 0; j < 2; ++j)
#pragma unroll
            for (int e = 0; e < 16; ++e)
                acc[i][j][e] = 0.f;

    // Cooperative frag staging: wave w copies its 4KB slice of the 16KB p-block.
    auto stage_issue = [&](int buf, int pn) {
        const char* gA = (const char*)frags + pn * 8192 + w * 2048 + lane * 16;
        const char* gW = (const char*)frags + 65536 + pn * 8192 + w * 2048 + lane * 16;
        char* lA = smem + buf * 16384 + w * 2048;
        char* lW = smem + buf * 16384 + 8192 + w * 2048;
        __builtin_amdgcn_global_load_lds((const __attribute__((address_space(1))) void*)gA,
                                         (__attribute__((address_space(3))) void*)lA, 16, 0, 0);
        __builtin_amdgcn_global_load_lds((const __attribute__((address_space(1))) void*)(gA + 1024),
                                         (__attribute__((address_space(3))) void*)(lA + 1024), 16, 0, 0);
        __builtin_amdgcn_global_load_lds((const __attribute__((address_space(1))) void*)gW,
                                         (__attribute__((address_space(3))) void*)lW, 16, 0, 0);
        __builtin_amdgcn_global_load_lds((const __attribute__((address_space(1))) void*)(gW + 1024),
                                         (__attribute__((address_space(3))) void*)(lW + 1024), 16, 0, 0);
    };

    stage_issue(0, 0);   // prologue: p=0 into buf0

#pragma unroll
    for (int p = 0; p < 8; ++p) {
        if (p < 7) {
            stage_issue((p + 1) & 1, p + 1);
            // 8 outstanding (p's 4 + p+1's 4); wait until only the newest 4 remain.
            asm volatile("s_waitcnt vmcnt(4)" ::: "memory");
        } else {
            asm volatile("s_waitcnt vmcnt(0)" ::: "memory");
        }
        __builtin_amdgcn_s_barrier();

        const unsigned short* LB = (const unsigned short*)(smem + (p & 1) * 16384);
        Frag8 af[2][4], wf[2][4];
#pragma unroll
        for (int t = 0; t < 2; ++t)
#pragma unroll
            for (int kc = 0; kc < 4; ++kc) {
                af[t][kc].v = *(const bf16x8*)(LB + (t * 4 + kc) * 512 + lane * 8);
                wf[t][kc].v = *(const bf16x8*)(LB + 4096 + (t * 4 + kc) * 512 + lane * 8);
            }
#pragma unroll
        for (int rb = 0; rb < 2; ++rb) {
#pragma unroll
            for (int cb = 0; cb < 2; ++cb) {
                // ---- Step A: T^T tile (kl rows rb*32.., ac cols cb*32..)
                f32x16 t;
#pragma unroll
                for (int e = 0; e < 16; ++e) t[e] = 0.f;
#pragma unroll
                for (int kc = 0; kc < 4; ++kc)
                    t = __builtin_amdgcn_mfma_f32_32x32x16_bf16(xf[rb][kc].v, af[cb][kc].v, t, 0, 0, 0);
                // ---- Repack C/D -> two B-operand frags, in-register.
                unsigned int wd[8];
#pragma unroll
                for (int h = 0; h < 8; ++h) wd[h] = pkbf(t[2 * h], t[2 * h + 1]);
                auto s02 = __builtin_amdgcn_permlane32_swap(wd[0], wd[2], false, false);
                auto s13 = __builtin_amdgcn_permlane32_swap(wd[1], wd[3], false, false);
                auto s46 = __builtin_amdgcn_permlane32_swap(wd[4], wd[6], false, false);
                auto s57 = __builtin_amdgcn_permlane32_swap(wd[5], wd[7], false, false);
                Frag8 tb0, tb1;
                tb0.u4[0] = s02[0]; tb0.u4[1] = s13[0]; tb0.u4[2] = s02[1]; tb0.u4[3] = s13[1];
                tb1.u4[0] = s46[0]; tb1.u4[1] = s57[0]; tb1.u4[2] = s46[1]; tb1.u4[3] = s57[1];
                // ---- Step B: Y^T[de][ac] += W^T[de][kl] * T^T[kl][ac]
                acc[0][cb] = __builtin_amdgcn_mfma_f32_32x32x16_bf16(wf[0][2 * rb].v,     tb0.v, acc[0][cb], 0, 0, 0);
                acc[0][cb] = __builtin_amdgcn_mfma_f32_32x32x16_bf16(wf[0][2 * rb + 1].v, tb1.v, acc[0][cb], 0, 0, 0);
                acc[1][cb] = __builtin_amdgcn_mfma_f32_32x32x16_bf16(wf[1][2 * rb].v,     tb0.v, acc[1][cb], 0, 0, 0);
                acc[1][cb] = __builtin_amdgcn_mfma_f32_32x32x16_bf16(wf[1][2 * rb + 1].v, tb1.v, acc[1][cb], 0, 0, 0);
            }
        }
        __builtin_amdgcn_s_barrier();   // all waves done reading buf[p&1]
    }

    // ---- Epilogue: per-cb LDS transpose (Y^T lane=col -> coalesced row stores) + bias
    // Reuses smem (all stage reads complete past the final barrier; no loads in flight).
    float* Yw = (float*)smem + w * (32 * Y_PITCH);
    float* ob = out + ((size_t)b << 12);
#pragma unroll
    for (int cb = 0; cb < 2; ++cb) {
        // stage: lane holds col ac = cb*32+l31; reg r -> de = mt*32 + (r&3)+8*(r>>2)+4*hi
#pragma unroll
        for (int mt = 0; mt < 2; ++mt)
#pragma unroll
            for (int rp = 0; rp < 8; ++rp) {
                int de = mt * 32 + 8 * (rp >> 1) + 2 * (rp & 1) + 4 * hi;
                float2 v;
                v.x = acc[mt][cb][2 * rp];
                v.y = acc[mt][cb][2 * rp + 1];
                *(float2*)(&Yw[l31 * Y_PITCH + de]) = v;   // 8B store, 8B-aligned
            }
        // read transposed + bias + coalesced store (512B contiguous per instr)
#pragma unroll
        for (int i = 0; i < 16; ++i) {
            int acl = 2 * i + hi;
            float2 v = *(float2*)(&Yw[acl * Y_PITCH + 2 * l31]);
            int o = (cb * 32 + acl) * 64 + 2 * l31;
            float2 bv = *(const float2*)(bias + o);
            v.x += bv.x;
            v.y += bv.y;
            *(float2*)(ob + o) = v;
        }
    }
}

extern "C" void kernel_launch(void* const* d_in, const int* in_sizes, int n_in,
                              void* d_out, int out_size, void* d_ws, size_t ws_size,
                              hipStream_t stream) {
    const float* x    = (const float*)d_in[0];
    const float* F0   = (const float*)d_in[1];
    const float* F1   = (const float*)d_in[2];
    const float* F2   = (const float*)d_in[3];
    const float* F3   = (const float*)d_in[4];
    const float* CL   = (const float*)d_in[5];
    const float* CR   = (const float*)d_in[6];
    const float* bias = (const float*)d_in[7];
    float* out = (float*)d_out;
    unsigned short* frags = (unsigned short*)d_ws;   // 128 KB

    const int B = in_sizes[0] / 4096;   // 4096

    ht_precompute<<<16, 256, 0, stream>>>(F0, F1, F2, F3, CL, CR, frags);
    ht_main<<<B / 4, 256, 0, stream>>>(x, frags, bias, out);
}